// Round 8
// baseline (84.023 us; speedup 1.0000x reference)
//
#include <hip/hip_runtime.h>

#define BMOL 256

// ragged sizes are static in the reference: n_b = 64 + (b % 129)
__device__ __forceinline__ int mol_n(int b) { return 64 + (b % 129); }
// prefix-sum offset of molecule b (one full cycle of 129 sums to 16512)
__device__ __forceinline__ int mol_off(int b) {
  int full = b / 129, rem = b % 129;
  return full * 16512 + 64 * rem + (rem * (rem - 1)) / 2;
}

__device__ __forceinline__ float frcp(float x) { return __builtin_amdgcn_rcpf(x); }

__global__ void zero_acc(float* acc) { acc[threadIdx.x] = 0.0f; }

// One WAVE per (molecule, upper-tri 64x64 tile pair, 4-row i-quad). lane <-> j.
// A = P[i][j] lane-coalesced; C = P[j][i0..i0+3] lane-private contiguous 48 B
// (16B-aligned since i0 % 4 == 0) -> 3 dwordx4. No LDS, no barrier.
// All loads issued up front and pinned live via empty asm (prevents the
// compiler from sinking them back into the compute loop) -> ONE latency
// exposure per wave; TLP (8 waves/SIMD, ~96 waves/CU of work) hides it.
__global__ __launch_bounds__(256) void pair_units(const float* __restrict__ pf,
                                                  const float* __restrict__ pos,
                                                  float* __restrict__ acc) {
  const int wave = threadIdx.x >> 6;
  const int lane = threadIdx.x & 63;
  const int u = blockIdx.x * 4 + wave;          // 24576 wave-units = 256 mol x 96
  const int b = u / 96;
  const int rest = u - b * 96;
  const int t = rest >> 4;                      // tile pair 0..5 (upper tri of 3x3)
  const int q = rest & 15;                      // i-quad within ti tile
  const int ti = (0x210100 >> (4 * t)) & 0xF;   // {0,0,1,0,1,2}[t]
  const int tj = (0x222110 >> (4 * t)) & 0xF;   // {0,1,1,2,2,2}[t]
  const int n = mol_n(b);
  const int j0 = tj * 64;
  const int i0 = ti * 64 + q * 4;
  if (j0 >= n || i0 >= n) return;               // dead wave: cheap uniform exit

  const int off = mol_off(b);
  const int j = j0 + lane;
  const bool jv = (j < n);

  // ---- issue ALL loads up front ----
  // C = P[j][i0..i0+3]: per-lane contiguous 12 floats, 16B-aligned -> 3 x float4
  float Cv[12];
  {
    const float4* cp = reinterpret_cast<const float4*>(
        pf + (size_t)(off + j) * 576 + (size_t)i0 * 3);
#pragma unroll
    for (int c = 0; c < 3; ++c) {
      float4 v = jv ? cp[c] : float4{0.f, 0.f, 0.f, 0.f};
      Cv[4 * c + 0] = v.x; Cv[4 * c + 1] = v.y;
      Cv[4 * c + 2] = v.z; Cv[4 * c + 3] = v.w;
    }
  }
  // A = P[i0+kk][j] (lane-coalesced) and pos_i (wave-uniform value)
  float Ax[4], Ay[4], Az[4], Pix[4], Piy[4], Piz[4];
#pragma unroll
  for (int kk = 0; kk < 4; ++kk) {
    const int i = i0 + kk;
    const bool iv = (i < n);
    float ax = 0.f, ay = 0.f, az = 0.f, px = 0.f, py = 0.f, pz = 0.f;
    if (iv && jv) {
      const float* ap = pf + (size_t)(off + i) * 576 + 3 * j;
      ax = ap[0]; ay = ap[1]; az = ap[2];
    }
    if (iv) {
      const float* pp = pos + (size_t)(off + i) * 3;
      px = pp[0]; py = pp[1]; pz = pp[2];
    }
    Ax[kk] = ax; Ay[kk] = ay; Az[kk] = az;
    Pix[kk] = px; Piy[kk] = py; Piz[kk] = pz;
  }
  float pjx = 0.f, pjy = 0.f, pjz = 0.f;
  if (jv) {
    const float* pp = pos + (size_t)(off + j) * 3;
    pjx = pp[0]; pjy = pp[1]; pjz = pp[2];
  }

  // ---- pin every loaded value live HERE: loads cannot sink below this ----
#pragma unroll
  for (int c = 0; c < 12; ++c) asm volatile("" : "+v"(Cv[c]));
#pragma unroll
  for (int kk = 0; kk < 4; ++kk)
    asm volatile("" : "+v"(Ax[kk]), "+v"(Ay[kk]), "+v"(Az[kk]),
                      "+v"(Pix[kk]), "+v"(Piy[kk]), "+v"(Piz[kk]));
  asm volatile("" : "+v"(pjx), "+v"(pjy), "+v"(pjz));

  // ---- pure register compute ----
  const float nf  = (float)n;
  const float sc1 = (nf - 1.f) / (nf * nf);
  const float sc2 = 1.f / nf;
  float accv = 0.f;

#pragma unroll
  for (int kk = 0; kk < 4; ++kk) {
    const int i = i0 + kk;
    if (i < n) {  // wave-uniform
      const float ax = Ax[kk], ay = Ay[kk], az = Az[kk];
      const float cx = Cv[3 * kk + 0], cy = Cv[3 * kk + 1], cz = Cv[3 * kk + 2];
      if (jv && j > i) {  // strict upper triangle: each unordered pair once
        const float rx = Pix[kk] - pjx, ry = Piy[kk] - pjy, rz = Piz[kk] - pjz;
        const float d2 = rx * rx + ry * ry + rz * rz;
        const float D  = (d2 > 0.f) ? __builtin_amdgcn_sqrtf(d2) : 0.f;
        const float pn2 = ax * ax + ay * ay + az * az;
        const float Pn  = (pn2 > 0.f) ? __builtin_amdgcn_sqrtf(pn2) : 0.f;
        const float qn2 = cx * cx + cy * cy + cz * cz;
        const float Qn  = (qn2 > 0.f) ? __builtin_amdgcn_sqrtf(qn2) : 0.f;
        const float invDeps = frcp(D + 1e-3f);
        const float pq = Pn * Qn;

        // term1 (symmetric): 2 * cos(P_ij,P_ji)/(D+1e-3)
        const float dot_pp = ax * cx + ay * cy + az * cz;
        const float t1 = 2.f * dot_pp * frcp(fmaxf(pq, 1e-18f)) * invDeps;
        // term2 (symmetric): 2 * (Pn-Qn)^2
        const float dpn = Pn - Qn;
        const float t2 = 2.f * dpn * dpn;
        // term3 (both orderings), merged denominator (one rcp):
        // |dot_ar|/(Pn*D) + |dot_cr|/(Qn*D) = (|dot_ar|*Qn + |dot_cr|*Pn)/(pq*D)
        const float dot_ar = ax * rx + ay * ry + az * rz;
        const float dot_cr = cx * rx + cy * ry + cz * rz;
        const float t3 = (fabsf(dot_ar) * Qn + fabsf(dot_cr) * Pn) *
                         frcp(fmaxf(pq * D, 1e-18f)) * invDeps;
        accv += sc1 * t1 + sc2 * (t2 - t3);
      }
      if (jv && j == i) {
        // diagonal of term1: cos = pn2/max(pn2,eps), D=0 -> /1e-3
        const float pn2 = ax * ax + ay * ay + az * az;
        accv += sc1 * (pn2 * frcp(fmaxf(pn2, 1e-18f))) * 1000.f;
      }
    }
  }

  // wave-64 reduce, one atomic per wave
  for (int o = 32; o > 0; o >>= 1) accv += __shfl_xor(accv, o, 64);
  if (lane == 0) atomicAdd(&acc[b], accv);
}

__global__ void finalize(const float* __restrict__ acc, float* __restrict__ out) {
  __shared__ float red[4];
  const int lane = threadIdx.x & 63, wave = threadIdx.x >> 6;
  float v = acc[threadIdx.x];
  for (int o = 32; o > 0; o >>= 1) v += __shfl_xor(v, o, 64);
  if (lane == 0) red[wave] = v;
  __syncthreads();
  if (threadIdx.x == 0)
    out[0] = (red[0] + red[1] + red[2] + red[3]) * (1.0f / (float)BMOL);
}

extern "C" void kernel_launch(void* const* d_in, const int* in_sizes, int n_in,
                              void* d_out, int out_size, void* d_ws, size_t ws_size,
                              hipStream_t stream) {
  const float* pf  = (const float*)d_in[0];   // (TOTAL, 192, 3) f32
  const float* pos = (const float*)d_in[1];   // (TOTAL, 3) f32
  float* acc = (float*)d_ws;                  // [256] per-molecule accumulators
  float* out = (float*)d_out;

  hipLaunchKernelGGL(zero_acc, dim3(1), dim3(BMOL), 0, stream, acc);
  hipLaunchKernelGGL(pair_units, dim3(BMOL * 96 / 4), dim3(256), 0, stream, pf, pos, acc);
  hipLaunchKernelGGL(finalize, dim3(1), dim3(BMOL), 0, stream, acc, out);
}

// Round 11
// 73.828 us; speedup vs baseline: 1.1381x; 1.1381x over previous
//
#include <hip/hip_runtime.h>

#define BMOL 256
#define TOTAL 32641
#define PT_DWORDS ((size_t)TOTAL * 576)          // 75,204,864 B transposed copy in ws

// ragged sizes are static in the reference: n_b = 64 + (b % 129)
__device__ __forceinline__ int mol_n(int b) { return 64 + (b % 129); }
// prefix-sum offset of molecule b (one full cycle of 129 sums to 16512)
__device__ __forceinline__ int mol_off(int b) {
  int full = b / 129, rem = b % 129;
  return full * 16512 + 64 * rem + (rem * (rem - 1)) / 2;
}

__device__ __forceinline__ float frcp(float x) { return __builtin_amdgcn_rcpf(x); }

__global__ void zero_acc(float* acc) {
  for (int k = threadIdx.x; k < BMOL * 16; k += 256) acc[k] = 0.0f;
}

// ---------------- Kernel A: per-molecule transpose PT[i][j] = P[j][i] ----------------
// Block = (molecule, 64-row j-tile, 32-col i-tile). Both global sides coalesced float4.
// LDS pitch 97 dwords: stage (b32 writes) and read-back are <=2-way bank aliased (free).
__global__ __launch_bounds__(256) void transpose_pf(const float* __restrict__ pf,
                                                    float* __restrict__ pt) {
  const int b  = blockIdx.x / 18;
  const int r  = blockIdx.x % 18;
  const int jt = r / 6;                      // source-row tile (64 rows)
  const int it = r % 6;                      // source-col tile (32 cols)
  const int n = mol_n(b);
  const int j0 = jt * 64, i0 = it * 32;
  if (j0 >= n || i0 >= n) return;            // uniform exit
  const int off = mol_off(b);

  __shared__ float L[64 * 97];               // L[jr][d], d = 3*il + c

  const int tid = threadIdx.x;
  // stage: 64 rows x 96 dwords, 4 threads/row x 24 dwords (6x float4 global reads)
  {
    const int jr = tid >> 2, q = tid & 3;
    const int j = j0 + jr;
    float v[24];
    if (j < n) {
      const float4* src = reinterpret_cast<const float4*>(
          pf + (size_t)(off + j) * 576 + 3 * i0 + q * 24);
#pragma unroll
      for (int m4 = 0; m4 < 6; ++m4) {
        float4 t = src[m4];
        v[4 * m4 + 0] = t.x; v[4 * m4 + 1] = t.y;
        v[4 * m4 + 2] = t.z; v[4 * m4 + 3] = t.w;
      }
    } else {
#pragma unroll
      for (int m = 0; m < 24; ++m) v[m] = 0.f;
    }
    float* dst = &L[jr * 97 + q * 24];
#pragma unroll
    for (int m = 0; m < 24; ++m) dst[m] = v[m];   // b32: banks (jr+24q+m)%32 -> <=2-way
  }
  __syncthreads();
  // write: 32 PT rows x 192 dwords, 8 threads/row x 24 dwords (6x float4 global writes)
  {
    const int il = tid >> 3, s = tid & 7;
    const int i = i0 + il;
    if (i < n) {
      float v[24];
#pragma unroll
      for (int m = 0; m < 24; ++m)                 // jr = 8s + m/3, c = m%3 (m/3,m%3 const)
        v[m] = L[(8 * s + m / 3) * 97 + 3 * il + (m % 3)];
      float4* dst = reinterpret_cast<float4*>(
          pt + (size_t)(off + i) * 576 + 3 * j0 + s * 24);
#pragma unroll
      for (int m4 = 0; m4 < 6; ++m4)
        dst[m4] = float4{v[4 * m4 + 0], v[4 * m4 + 1], v[4 * m4 + 2], v[4 * m4 + 3]};
    }
  }
}

// ---------------- Kernel B: pair terms over upper-tri octet pairs ----------------
// Wave = (molecule, octet pair oi<=oj), lane = (ki,kj) in the 8x8 block.
// A = P[i][j] from pf, C = P[j][i] from PT -- BOTH coalesced (~16 lines/instr).
// oi<oj: both orderings from one block (factor 2 + both term3s). oi==oj: single
// ordering; diagonal falls out naturally (cos=1, D=0 -> +1000), term3 gated j!=i.
__global__ __launch_bounds__(256) void pair_oct(const float* __restrict__ pf,
                                                const float* __restrict__ pt,
                                                const float* __restrict__ pos,
                                                float* __restrict__ acc) {
  const int wave = threadIdx.x >> 6;
  const int lane = threadIdx.x & 63;
  const int u = blockIdx.x * 4 + wave;       // 256 mol x 300 octet-pairs
  const int b = u / 300;
  const int pr = u - b * 300;
  // decode pr = oj*(oj+1)/2 + oi, 0 <= oi <= oj < 24
  int oj = (int)((__builtin_amdgcn_sqrtf(8.f * (float)pr + 1.f) - 1.f) * 0.5f);
  if ((oj + 1) * (oj + 2) / 2 <= pr) ++oj;
  if (oj * (oj + 1) / 2 > pr) --oj;
  const int oi = pr - oj * (oj + 1) / 2;
  const int n = mol_n(b);
  const int j0 = oj * 8, i0 = oi * 8;
  if (j0 >= n) return;                       // uniform exit (oi<=oj => i0<=j0)
  const int off = mol_off(b);

  const int ki = lane >> 3, kj = lane & 7;
  const int i = i0 + ki, j = j0 + kj;
  const bool iv = (i < n), jv = (j < n), act = iv && jv;

  float ax = 0.f, ay = 0.f, az = 0.f, cx = 0.f, cy = 0.f, cz = 0.f;
  if (act) {
    const float* ap = pf + (size_t)(off + i) * 576 + 3 * j;
    ax = ap[0]; ay = ap[1]; az = ap[2];
    const float* cp = pt + (size_t)(off + i) * 576 + 3 * j;   // = P[j][i]
    cx = cp[0]; cy = cp[1]; cz = cp[2];
  }
  float pix = 0.f, piy = 0.f, piz = 0.f, pjx = 0.f, pjy = 0.f, pjz = 0.f;
  if (iv) {
    const float* pp = pos + (size_t)(off + i) * 3;
    pix = pp[0]; piy = pp[1]; piz = pp[2];
  }
  if (jv) {
    const float* pp = pos + (size_t)(off + j) * 3;
    pjx = pp[0]; pjy = pp[1]; pjz = pp[2];
  }

  const float nf  = (float)n;
  const float sc1 = (nf - 1.f) / (nf * nf);
  const float sc2 = 1.f / nf;
  const bool  dbl = (oi < oj);               // wave-uniform
  float accv = 0.f;

  if (act) {
    const float rx = pix - pjx, ry = piy - pjy, rz = piz - pjz;
    const float d2 = rx * rx + ry * ry + rz * rz;
    const float D  = (d2 > 0.f) ? __builtin_amdgcn_sqrtf(d2) : 0.f;
    const float pn2 = ax * ax + ay * ay + az * az;
    const float Pn  = (pn2 > 0.f) ? __builtin_amdgcn_sqrtf(pn2) : 0.f;
    const float qn2 = cx * cx + cy * cy + cz * cz;
    const float Qn  = (qn2 > 0.f) ? __builtin_amdgcn_sqrtf(qn2) : 0.f;
    const float invDeps = frcp(D + 1e-3f);
    const float pq = Pn * Qn;

    // term1: cos(P_ij, P_ji) / (D+1e-3)   (diag: cos=1, D=0 -> *1000 automatically)
    const float dot_pp = ax * cx + ay * cy + az * cz;
    const float t1 = dot_pp * frcp(fmaxf(pq, 1e-18f)) * invDeps;
    // term2: (Pn - Qn)^2                  (diag: 0 automatically)
    const float dpn = Pn - Qn;
    const float t2 = dpn * dpn;
    // term3 pieces
    const float dot_ar = ax * rx + ay * ry + az * rz;
    const float dot_cr = cx * rx + cy * ry + cz * rz;
    const float t3a = fabsf(dot_ar) * frcp(fmaxf(Pn * D, 1e-18f)) * invDeps;
    const float t3c = fabsf(dot_cr) * frcp(fmaxf(Qn * D, 1e-18f)) * invDeps;

    if (dbl) {  // i<j strictly: both orderings
      accv = sc1 * 2.f * t1 + sc2 * (2.f * t2 - (t3a + t3c));
    } else {    // oi==oj: single ordering; term3 only off-diagonal
      accv = sc1 * t1 + sc2 * (t2 - ((j != i) ? t3a : 0.f));
    }
  }

  // wave-64 reduce, one padded atomic per wave
  for (int o = 32; o > 0; o >>= 1) accv += __shfl_xor(accv, o, 64);
  if (lane == 0) atomicAdd(&acc[b * 16], accv);
}

__global__ void finalize(const float* __restrict__ acc, float* __restrict__ out) {
  __shared__ float red[4];
  const int lane = threadIdx.x & 63, wave = threadIdx.x >> 6;
  float v = acc[threadIdx.x * 16];
  for (int o = 32; o > 0; o >>= 1) v += __shfl_xor(v, o, 64);
  if (lane == 0) red[wave] = v;
  __syncthreads();
  if (threadIdx.x == 0)
    out[0] = (red[0] + red[1] + red[2] + red[3]) * (1.0f / (float)BMOL);
}

extern "C" void kernel_launch(void* const* d_in, const int* in_sizes, int n_in,
                              void* d_out, int out_size, void* d_ws, size_t ws_size,
                              hipStream_t stream) {
  const float* pf  = (const float*)d_in[0];   // (TOTAL, 192, 3) f32
  const float* pos = (const float*)d_in[1];   // (TOTAL, 3) f32
  float* pt  = (float*)d_ws;                                  // 75.2 MB transposed copy
  float* acc = (float*)d_ws + PT_DWORDS;                      // 256 x 16 padded accum
  float* out = (float*)d_out;

  hipLaunchKernelGGL(zero_acc, dim3(1), dim3(256), 0, stream, acc);
  hipLaunchKernelGGL(transpose_pf, dim3(BMOL * 18), dim3(256), 0, stream, pf, pt);
  hipLaunchKernelGGL(pair_oct, dim3(BMOL * 300 / 4), dim3(256), 0, stream,
                     pf, pt, pos, acc);
  hipLaunchKernelGGL(finalize, dim3(1), dim3(256), 0, stream, acc, out);
}

// Round 12
// 29.890 us; speedup vs baseline: 2.8110x; 2.4700x over previous
//
#include <hip/hip_runtime.h>

#define BMOL 256
#define PPM 300                 // 24*25/2 upper-tri octet pairs per molecule (T<=24)
#define NSLOT (BMOL * 8)        // spread accumulator slots, stride 16 dwords (1 line each)

// ragged sizes are static in the reference: n_b = 64 + (b % 129)
__device__ __forceinline__ int mol_n(int b) { return 64 + (b % 129); }
// prefix-sum offset of molecule b (one full cycle of 129 sums to 16512)
__device__ __forceinline__ int mol_off(int b) {
  int full = b / 129, rem = b % 129;
  return full * 16512 + 64 * rem + (rem * (rem - 1)) / 2;
}
__device__ __forceinline__ float frcp(float x) { return __builtin_amdgcn_rcpf(x); }

__global__ __launch_bounds__(256) void zero_acc(float* acc) {
  const int idx = blockIdx.x * 256 + threadIdx.x;
  if (idx < NSLOT) acc[idx * 16] = 0.0f;
}

// One WAVE per (molecule, upper-tri octet pair oi<=oj); lane = (ki,kj) in the 8x8 block.
// A = P[i][j] and C = P[j][i] both read DIRECTLY from pf (each ~8-row mild divergence).
// Branchless clamped loads, all issued before sched_barrier(0) -> batched, one latency
// exposure per wave. No LDS, no block barrier. Atomic spread over 2048 padded lines.
__global__ __launch_bounds__(256) void pair_oct(const float* __restrict__ pf,
                                                const float* __restrict__ pos,
                                                float* __restrict__ acc) {
  const int wave = threadIdx.x >> 6;
  const int lane = threadIdx.x & 63;
  const int u = blockIdx.x * 4 + wave;       // 256 mol x 300 octet-pairs = 76800 waves
  const int b = u / PPM;                     // constant div -> mulhi
  const int pr = u - b * PPM;
  // decode pr = oj*(oj+1)/2 + oi, 0 <= oi <= oj < 24
  int oj = (int)((__builtin_amdgcn_sqrtf(8.f * (float)pr + 1.f) - 1.f) * 0.5f);
  if ((oj + 1) * (oj + 2) / 2 <= pr) ++oj;
  if (oj * (oj + 1) / 2 > pr) --oj;
  const int oi = pr - oj * (oj + 1) / 2;
  const int n = mol_n(b);
  const int j0 = oj * 8, i0 = oi * 8;
  if (j0 >= n) return;                       // dead wave: uniform cheap exit (i0<=j0)
  const int off = mol_off(b);

  const int ki = lane >> 3, kj = lane & 7;
  const int i = i0 + ki, j = j0 + kj;
  const bool act = (i < n) && (j < n);
  const int ic = min(i, n - 1), jc = min(j, n - 1);   // clamp: loads always valid

  // ---- all loads, branchless, batch-issued ----
  const float* ap = pf + (size_t)(off + ic) * 576 + 3 * jc;   // A = P[i][j]
  const float ax = ap[0], ay = ap[1], az = ap[2];
  const float* cp = pf + (size_t)(off + jc) * 576 + 3 * ic;   // C = P[j][i]
  const float cx = cp[0], cy = cp[1], cz = cp[2];
  const float* pip = pos + (size_t)(off + ic) * 3;
  const float pix = pip[0], piy = pip[1], piz = pip[2];
  const float* pjp = pos + (size_t)(off + jc) * 3;
  const float pjx = pjp[0], pjy = pjp[1], pjz = pjp[2];
  __builtin_amdgcn_sched_barrier(0);         // nothing crosses: loads stay hoisted

  // ---- pure register compute ----
  const float nf  = (float)n;
  const float sc1 = (nf - 1.f) / (nf * nf);
  const float sc2 = 1.f / nf;
  const bool  dbl = (oi < oj);               // wave-uniform

  const float rx = pix - pjx, ry = piy - pjy, rz = piz - pjz;
  const float d2 = rx * rx + ry * ry + rz * rz;
  const float D  = (d2 > 0.f) ? __builtin_amdgcn_sqrtf(d2) : 0.f;
  const float pn2 = ax * ax + ay * ay + az * az;
  const float Pn  = (pn2 > 0.f) ? __builtin_amdgcn_sqrtf(pn2) : 0.f;
  const float qn2 = cx * cx + cy * cy + cz * cz;
  const float Qn  = (qn2 > 0.f) ? __builtin_amdgcn_sqrtf(qn2) : 0.f;
  const float invDeps = frcp(D + 1e-3f);
  const float pq = Pn * Qn;

  // term1: cos(P_ij,P_ji)/(D+1e-3)   (diag: cos=1, D=0 -> *1000 automatically)
  const float dot_pp = ax * cx + ay * cy + az * cz;
  const float t1 = dot_pp * frcp(fmaxf(pq, 1e-18f)) * invDeps;
  // term2: (Pn-Qn)^2                 (diag: 0 automatically)
  const float dpn = Pn - Qn;
  const float t2 = dpn * dpn;
  // term3 pieces (off-diagonal only on the diag-block path)
  const float dot_ar = ax * rx + ay * ry + az * rz;
  const float dot_cr = cx * rx + cy * ry + cz * rz;
  const float t3a = fabsf(dot_ar) * frcp(fmaxf(Pn * D, 1e-18f)) * invDeps;
  const float t3c = fabsf(dot_cr) * frcp(fmaxf(Qn * D, 1e-18f)) * invDeps;

  float val;
  if (dbl) {   // oi<oj: whole block strictly off-diagonal, both orderings
    val = sc1 * 2.f * t1 + sc2 * (2.f * t2 - (t3a + t3c));
  } else {     // oi==oj: single ordering; term3 gated off-diagonal
    val = sc1 * t1 + sc2 * (t2 - ((j != i) ? t3a : 0.f));
  }
  float accv = act ? val : 0.f;

  // wave-64 reduce, one spread-padded atomic per wave (~37 atomics/line)
  for (int o = 32; o > 0; o >>= 1) accv += __shfl_xor(accv, o, 64);
  if (lane == 0) atomicAdd(&acc[(b * 8 + (u & 7)) * 16], accv);
}

__global__ __launch_bounds__(256) void finalize(const float* __restrict__ acc,
                                                float* __restrict__ out) {
  __shared__ float red[4];
  float v = 0.f;
  for (int s = threadIdx.x; s < NSLOT; s += 256) v += acc[s * 16];
  for (int o = 32; o > 0; o >>= 1) v += __shfl_xor(v, o, 64);
  if ((threadIdx.x & 63) == 0) red[threadIdx.x >> 6] = v;
  __syncthreads();
  if (threadIdx.x == 0)
    out[0] = (red[0] + red[1] + red[2] + red[3]) * (1.0f / (float)BMOL);
}

extern "C" void kernel_launch(void* const* d_in, const int* in_sizes, int n_in,
                              void* d_out, int out_size, void* d_ws, size_t ws_size,
                              hipStream_t stream) {
  const float* pf  = (const float*)d_in[0];   // (TOTAL, 192, 3) f32
  const float* pos = (const float*)d_in[1];   // (TOTAL, 3) f32
  float* acc = (float*)d_ws;                  // 2048 slots x 16 dwords = 128 KB
  float* out = (float*)d_out;

  hipLaunchKernelGGL(zero_acc, dim3(NSLOT / 256), dim3(256), 0, stream, acc);
  hipLaunchKernelGGL(pair_oct, dim3(BMOL * PPM / 4), dim3(256), 0, stream, pf, pos, acc);
  hipLaunchKernelGGL(finalize, dim3(1), dim3(256), 0, stream, acc, out);
}